// Round 13
// baseline (1006.024 us; speedup 1.0000x reference)
//
#include <hip/hip_runtime.h>
#include <math.h>

#define D 128
#define NG 64
#define NG2 128
#define NSTEPS 5

using short8 = __attribute__((ext_vector_type(8))) short;
using f32x4  = __attribute__((ext_vector_type(4))) float;
using f32x2  = __attribute__((ext_vector_type(2))) float;

// fast, overflow-safe transcendentals (v_exp_f32 + v_rcp_f32)
__device__ __forceinline__ float sigf(float x) {
  float e = __expf(-fabsf(x));
  float inv = __fdividef(1.f, 1.f + e);
  return x >= 0.f ? inv : e * inv;
}
__device__ __forceinline__ float tanhf_fast(float x) {
  float e = __expf(-2.f * fabsf(x));
  float r = (1.f - e) * __fdividef(1.f, 1.f + e);
  return x >= 0.f ? r : -r;
}
__device__ __forceinline__ float lrelu(float x) { return x > 0.f ? x : 0.2f * x; }
__device__ __forceinline__ short f2bf(float x) {
  unsigned u = __float_as_uint(x);
  u += 0x7fff + ((u >> 16) & 1);
  return (short)(u >> 16);
}
__device__ __forceinline__ unsigned pk2(float x, float y) {
  return ((unsigned)(unsigned short)f2bf(y) << 16) | (unsigned short)f2bf(x);
}
__device__ __forceinline__ float bflo(unsigned v) { return __uint_as_float(v << 16); }
__device__ __forceinline__ float bfhi(unsigned v) { return __uint_as_float(v & 0xffff0000u); }
__device__ __forceinline__ float bf2f(short s) {
  return __uint_as_float(((unsigned)(unsigned short)s) << 16);
}
__device__ __forceinline__ unsigned char f2fp8(float x) {
  int p = __builtin_amdgcn_cvt_pk_fp8_f32(x, x, 0, false);
  return (unsigned char)(p & 0xff);
}

// ---------- pack helpers ----------
__device__ __forceinline__ void packK128(const float* __restrict__ W,
                                         short* __restrict__ P, int i) {
  int j = i & 7;
  int lane = (i >> 3) & 63;
  int kt = (i >> 9) & 3;
  int nt = i >> 11;
  int c = nt * 16 + (lane & 15);
  int k = kt * 32 + ((lane >> 4) << 3) + j;
  P[i] = f2bf(W[c * 128 + k]);
}
__device__ __forceinline__ void packA512f(const float* __restrict__ W_et,
                                          short* __restrict__ P, int i) {
  int j = i & 7;
  int lane = (i >> 3) & 63;
  int kt = (i >> 9) & 15;
  int nt = i >> 13;
  int c = nt * 16 + (lane & 15);
  int k = kt * 32 + ((lane >> 4) << 3) + j;
  P[i] = f2bf(W_et[(k >> 7) * 16384 + c * 128 + (k & 127)]);
}

// ---------- mega setup: packs + init hb (bf16) + hq (fp8 shadow) + zero deg/gcnt ----------
__global__ __launch_bounds__(256) void k_setup(const float* __restrict__ W_et,
    const float* __restrict__ W_ih, const float* __restrict__ W_hh,
    const float* __restrict__ W_fc, const float* __restrict__ f1,
    const float* __restrict__ f2, short* __restrict__ WaP, short* __restrict__ WihP,
    short* __restrict__ WhhP, short* __restrict__ WfcP, short* __restrict__ hb,
    unsigned char* __restrict__ hq,
    int* __restrict__ deg, int* __restrict__ gcnt, int N2, int Nd4) {
  const int sA = 65536, sB = 49152, sC = 49152, sD = 32768;
  int sE = N2, sF = NG2;
  long sG = 2L * Nd4;
  long tot = (long)(sA + sB + sC + sD) + sE + sF + sG;
  for (long ii = (long)blockIdx.x * blockDim.x + threadIdx.x; ii < tot;
       ii += (long)gridDim.x * blockDim.x) {
    long r = ii;
    if (r < sA) { packA512f(W_et, WaP, (int)r); continue; }
    r -= sA;
    if (r < sB) { packK128(W_ih, WihP, (int)r); continue; }
    r -= sB;
    if (r < sC) { packK128(W_hh, WhhP, (int)r); continue; }
    r -= sC;
    if (r < sD) { packK128(W_fc, WfcP, (int)r); continue; }
    r -= sD;
    if (r < sE) { deg[r] = 0; continue; }
    r -= sE;
    if (r < sF) { gcnt[r] = 0; continue; }
    r -= sF;
    {
      int i = (int)r;
      float4 v = (i < Nd4) ? ((const float4*)f1)[i] : ((const float4*)f2)[i - Nd4];
      ((uint2*)hb)[i] = make_uint2(pk2(v.x, v.y), pk2(v.z, v.w));
      int q = __builtin_amdgcn_cvt_pk_fp8_f32(v.x, v.y, 0, false);
      q = __builtin_amdgcn_cvt_pk_fp8_f32(v.z, v.w, q, true);
      ((unsigned*)hq)[i] = (unsigned)q;
    }
  }
}

// ---------- hist (XCD-sliced edge blocks) + gid fill/count (node blocks) ----------
__global__ __launch_bounds__(256) void k_histgid(const int* __restrict__ dst1,
    const int* __restrict__ dst2, const int* __restrict__ gid1,
    const int* __restrict__ gid2, int E, int N, int* __restrict__ deg,
    int* __restrict__ gidc, int* __restrict__ gcnt, int EB, int N2) {
  __shared__ int cnt[NG2];
  if ((int)blockIdx.x < EB) {
    int slice = blockIdx.x & 7;
    int bls = blockIdx.x >> 3;
    int nbs = EB >> 3;
    int W = (N2 + 7) >> 3;
    int lo = slice * W, hi = lo + W;
    for (int e = bls * 256 + threadIdx.x; e < 2 * E; e += nbs * 256) {
      int d = (e < E) ? dst1[e] : dst2[e - E] + N;
      if (d >= lo && d < hi) atomicAdd(&deg[d], 1);
    }
  } else {
    int t = threadIdx.x;
    if (t < NG2) cnt[t] = 0;
    __syncthreads();
    int i = (blockIdx.x - EB) * 256 + t;
    if (i < 2 * N) {
      int g = (i < N) ? gid1[i] : gid2[i - N] + NG;
      gidc[i] = g;
      atomicAdd(&cnt[g], 1);
    }
    __syncthreads();
    if (t < NG2 && cnt[t]) atomicAdd(&gcnt[t], cnt[t]);
  }
}

__global__ __launch_bounds__(256) void k_scan_a(const int* __restrict__ deg, int n,
                                                int* __restrict__ bsum) {
  int base = blockIdx.x * 1024 + threadIdx.x * 4;
  int s = 0;
  if (base + 3 < n) {
    int4 v = *(const int4*)(deg + base);
    s = v.x + v.y + v.z + v.w;
  } else {
    for (int k = 0; k < 4; ++k) if (base + k < n) s += deg[base + k];
  }
  #pragma unroll
  for (int off = 32; off; off >>= 1) s += __shfl_xor(s, off);
  __shared__ int ws[4];
  if ((threadIdx.x & 63) == 0) ws[threadIdx.x >> 6] = s;
  __syncthreads();
  if (threadIdx.x == 0) bsum[blockIdx.x] = ws[0] + ws[1] + ws[2] + ws[3];
}

__global__ __launch_bounds__(1024) void k_scan_b(const int* __restrict__ bsum,
                                                 int* __restrict__ boffs, int nb) {
  int tid = threadIdx.x;
  int v = (tid < nb) ? bsum[tid] : 0;
  int lane = tid & 63, wv = tid >> 6;
  int x = v;
  #pragma unroll
  for (int off = 1; off < 64; off <<= 1) {
    int y = __shfl_up(x, off);
    if (lane >= off) x += y;
  }
  __shared__ int wsum[16];
  if (lane == 63) wsum[wv] = x;
  __syncthreads();
  if (tid < 16) {
    int u = wsum[tid];
    #pragma unroll
    for (int off = 1; off < 16; off <<= 1) {
      int y = __shfl_up(u, off);
      if (tid >= off) u += y;
    }
    wsum[tid] = u;
  }
  __syncthreads();
  int woff = wv ? wsum[wv - 1] : 0;
  if (tid < nb) boffs[tid] = woff + x - v;
}

__global__ __launch_bounds__(256) void k_scan_c(const int* __restrict__ deg,
    const int* __restrict__ boffs, int* __restrict__ row_ofs,
    int* __restrict__ cursor, int n) {
  int base = blockIdx.x * 1024 + threadIdx.x * 4;
  int v[4] = {0, 0, 0, 0};
  if (base + 3 < n) {
    int4 t = *(const int4*)(deg + base);
    v[0] = t.x; v[1] = t.y; v[2] = t.z; v[3] = t.w;
  } else {
    for (int k = 0; k < 4; ++k) if (base + k < n) v[k] = deg[base + k];
  }
  int s = v[0] + v[1] + v[2] + v[3];
  int lane = threadIdx.x & 63, wv = threadIdx.x >> 6;
  int x = s;
  #pragma unroll
  for (int off = 1; off < 64; off <<= 1) {
    int y = __shfl_up(x, off);
    if (lane >= off) x += y;
  }
  __shared__ int wsum[4];
  if (lane == 63) wsum[wv] = x;
  __syncthreads();
  int woff = 0;
  for (int w = 0; w < wv; ++w) woff += wsum[w];
  int run = boffs[blockIdx.x] + woff + x - s;
  #pragma unroll
  for (int k = 0; k < 4; ++k) {
    int i = base + k;
    if (i < n) {
      cursor[i] = run;
      run += v[k];
      row_ofs[i + 1] = run;
    }
  }
  if (blockIdx.x == 0 && threadIdx.x == 0) row_ofs[0] = 0;
}

// scatter: csr_se = src*1024 + etype. XCD-sliced by dst (blockIdx&7 = slice).
__global__ __launch_bounds__(256) void k_scatter(const int* __restrict__ src1,
    const int* __restrict__ dst1, const int* __restrict__ ety1,
    const int* __restrict__ src2, const int* __restrict__ dst2,
    const int* __restrict__ ety2, int E, int N, int* __restrict__ cursor,
    int* __restrict__ csr_se, int N2) {
  int slice = blockIdx.x & 7;
  int bls = blockIdx.x >> 3;
  int nbs = gridDim.x >> 3;
  int W = (N2 + 7) >> 3;
  int lo = slice * W, hi = lo + W;
  for (int e = bls * 256 + threadIdx.x; e < 2 * E; e += nbs * 256) {
    int d = (e < E) ? dst1[e] : dst2[e - E] + N;
    if (d < lo || d >= hi) continue;
    int s, et;
    if (e < E) { s = src1[e]; et = ety1[e]; }
    else { s = src2[e - E] + N; et = ety2[e - E]; }
    int p = atomicAdd(&cursor[d], 1);
    csr_se[p] = (s << 10) + et;
  }
}

// ---------- FULLY FUSED STEP (r10 structure): fp8 gather (1 node/wave) ->
// et-GEMM (LDS, depth-4 b-prefetch ring) -> GRU -> hb/hq new. Double-buffered h.
// launch_bounds(1024,8) pins the 64-VGPR/full-occupancy budget so the ring fits. ----------
__global__ __launch_bounds__(1024, 8) void k_step(const unsigned char* __restrict__ hq_old,
    const short* __restrict__ hb_old, unsigned char* __restrict__ hq_new,
    short* __restrict__ hb_new,
    const int* __restrict__ row_ofs, const int* __restrict__ csr_se,
    const short* __restrict__ WaP, const float* __restrict__ b_et,
    const short* __restrict__ Pih, const short* __restrict__ Phh,
    const float* __restrict__ b_ih, const float* __restrict__ b_hh, int M) {
  __shared__ short Stile[16 * 512];        // 16 KB per-etype sums, swizzled
  __shared__ float lcnt[16][4];
  __shared__ short abt[16 * 128];          // 4 KB ab tile, swizzled
  __shared__ short hin[16 * 128];          // 4 KB hb_old tile, swizzled
  __shared__ short hbs[16 * 128];          // 4 KB out bf16
  __shared__ unsigned char hqs[16 * 128];  // 2 KB out fp8
  int tid = threadIdx.x;
  int lane = tid & 63, wave = tid >> 6;   // wave = 0..15
  int row0 = blockIdx.x * 16;
  int quad = lane >> 4, l15 = lane & 15;

  // ---- phase 1: per-etype fp8 gather; wave handles node row0 + wave ----
  {
    int li = wave;
    int node = row0 + li;
    f32x2 A0 = {0.f, 0.f}, A1 = {0.f, 0.f}, A2 = {0.f, 0.f}, A3 = {0.f, 0.f};
    int c0 = 0, c1 = 0, c2 = 0, c3 = 0;
    const char* hqb = (const char*)hq_old;
    if (node < M) {
      int beg = row_ofs[node], end = row_ofs[node + 1];
      #define ACC(ET, V) do { \
          f32x2 t_ = __builtin_amdgcn_cvt_pk_f32_fp8((unsigned)(V), false); \
          if (ET == 0)      { A0 += t_; ++c0; } \
          else if (ET == 1) { A1 += t_; ++c1; } \
          else if (ET == 2) { A2 += t_; ++c2; } \
          else              { A3 += t_; ++c3; } } while (0)
      for (int base = beg; base < end; base += 64) {
        int nv = end - base; if (nv > 64) nv = 64;
        int r = (lane < nv) ? csr_se[base + lane] : 0;
        int j = 0;
        for (; j + 16 <= nv; j += 16) {
          int rr[16];
          #pragma unroll
          for (int k = 0; k < 16; ++k) rr[k] = __builtin_amdgcn_readlane(r, j + k);
          unsigned short v[16];
          #pragma unroll
          for (int k = 0; k < 16; ++k)
            v[k] = ((const unsigned short*)(hqb + (rr[k] >> 3)))[lane];
          #pragma unroll
          for (int k = 0; k < 16; ++k) ACC(rr[k] & 3, v[k]);
        }
        for (; j + 8 <= nv; j += 8) {
          int rr[8];
          #pragma unroll
          for (int k = 0; k < 8; ++k) rr[k] = __builtin_amdgcn_readlane(r, j + k);
          unsigned short v[8];
          #pragma unroll
          for (int k = 0; k < 8; ++k)
            v[k] = ((const unsigned short*)(hqb + (rr[k] >> 3)))[lane];
          #pragma unroll
          for (int k = 0; k < 8; ++k) ACC(rr[k] & 3, v[k]);
        }
        for (; j + 4 <= nv; j += 4) {
          int rr[4];
          #pragma unroll
          for (int k = 0; k < 4; ++k) rr[k] = __builtin_amdgcn_readlane(r, j + k);
          unsigned short v[4];
          #pragma unroll
          for (int k = 0; k < 4; ++k)
            v[k] = ((const unsigned short*)(hqb + (rr[k] >> 3)))[lane];
          #pragma unroll
          for (int k = 0; k < 4; ++k) ACC(rr[k] & 3, v[k]);
        }
        for (; j < nv; ++j) {
          int rr = __builtin_amdgcn_readlane(r, j);
          unsigned short v = ((const unsigned short*)(hqb + (rr >> 3)))[lane];
          ACC(rr & 3, v);
        }
      }
      #undef ACC
    }
    int swz = (li & 7) << 4;
    unsigned* ld = (unsigned*)Stile;
    ld[(li * 1024 + ((lane * 4      ) ^ swz)) >> 2] = pk2(A0[0], A0[1]);
    ld[(li * 1024 + ((lane * 4 + 256) ^ swz)) >> 2] = pk2(A1[0], A1[1]);
    ld[(li * 1024 + ((lane * 4 + 512) ^ swz)) >> 2] = pk2(A2[0], A2[1]);
    ld[(li * 1024 + ((lane * 4 + 768) ^ swz)) >> 2] = pk2(A3[0], A3[1]);
    if (lane == 0) {
      lcnt[li][0] = (float)c0; lcnt[li][1] = (float)c1;
      lcnt[li][2] = (float)c2; lcnt[li][3] = (float)c3;
    }
  }
  __syncthreads();

  // ---- phase 3: waves 0-7 et-GEMM (depth-4 b-ring) -> abt; waves 8-11 stage hb_old ----
  if (wave < 8) {
    int swz = (l15 & 7) << 4;
    int nt = wave;
    const short8* bp = ((const short8*)WaP) + ((size_t)nt * 16) * 64 + lane;
    short8 br[4];
    #pragma unroll
    for (int k = 0; k < 4; ++k) br[k] = bp[(size_t)k * 64];
    f32x4 acc = {0.f, 0.f, 0.f, 0.f};
    #pragma unroll
    for (int kt = 0; kt < 16; ++kt) {
      int boff = l15 * 1024 + ((kt * 64 + quad * 16) ^ swz);
      short8 a = *(const short8*)((const char*)Stile + boff);
      short8 b = br[kt & 3];
      if (kt + 4 < 16) br[kt & 3] = bp[(size_t)(kt + 4) * 64];
      acc = __builtin_amdgcn_mfma_f32_16x16x32_bf16(a, b, acc, 0, 0, 0);
    }
    int c = nt * 16 + l15;
    float be0 = b_et[c], be1 = b_et[128 + c], be2 = b_et[256 + c], be3 = b_et[384 + c];
    #pragma unroll
    for (int reg = 0; reg < 4; ++reg) {
      int lr = quad * 4 + reg;
      float v = acc[reg] + lcnt[lr][0] * be0 + lcnt[lr][1] * be1
                         + lcnt[lr][2] * be2 + lcnt[lr][3] * be3;
      int bo = (lr * 256 + c * 2) ^ ((lr & 7) << 4);
      *(short*)((char*)abt + bo) = f2bf(v);
    }
  } else if (wave < 12) {
    int t2 = tid - 512;                  // 0..255
    int row = t2 >> 4;                   // 16 rows
    int col8 = t2 & 15;                  // 16 chunks of 8 shorts
    int r = row0 + row;
    uint4 v = make_uint4(0, 0, 0, 0);
    if (r < M) v = *(const uint4*)(hb_old + (size_t)r * 128 + col8 * 8);
    int bo = (row * 256 + col8 * 16) ^ ((row & 7) << 4);
    *(uint4*)((char*)hin + bo) = v;
  }
  __syncthreads();

  // ---- phase 5: waves 0-7 GRU; wave owns output col tile nt = wave ----
  if (wave < 8) {
    int nt = wave;
    size_t li = ((size_t)lane) * 8;
    f32x4 accr = {0.f,0.f,0.f,0.f}, accz = {0.f,0.f,0.f,0.f};
    f32x4 acci = {0.f,0.f,0.f,0.f}, acch = {0.f,0.f,0.f,0.f};
    #pragma unroll
    for (int kt = 0; kt < 4; ++kt) {
      int ao = (l15 * 256 + (kt * 64 + quad * 16)) ^ ((l15 & 7) << 4);
      short8 fa = *(const short8*)((const char*)abt + ao);
      short8 fh = *(const short8*)((const char*)hin + ao);
      short8 wr = *(const short8*)(Pih + ((size_t)((nt     ) * 4 + kt) * 64) * 8 + li);
      short8 wz = *(const short8*)(Pih + ((size_t)((nt +  8) * 4 + kt) * 64) * 8 + li);
      short8 wn = *(const short8*)(Pih + ((size_t)((nt + 16) * 4 + kt) * 64) * 8 + li);
      short8 ur = *(const short8*)(Phh + ((size_t)((nt     ) * 4 + kt) * 64) * 8 + li);
      short8 uz = *(const short8*)(Phh + ((size_t)((nt +  8) * 4 + kt) * 64) * 8 + li);
      short8 un = *(const short8*)(Phh + ((size_t)((nt + 16) * 4 + kt) * 64) * 8 + li);
      accr = __builtin_amdgcn_mfma_f32_16x16x32_bf16(fa, wr, accr, 0, 0, 0);
      accr = __builtin_amdgcn_mfma_f32_16x16x32_bf16(fh, ur, accr, 0, 0, 0);
      accz = __builtin_amdgcn_mfma_f32_16x16x32_bf16(fa, wz, accz, 0, 0, 0);
      accz = __builtin_amdgcn_mfma_f32_16x16x32_bf16(fh, uz, accz, 0, 0, 0);
      acci = __builtin_amdgcn_mfma_f32_16x16x32_bf16(fa, wn, acci, 0, 0, 0);
      acch = __builtin_amdgcn_mfma_f32_16x16x32_bf16(fh, un, acch, 0, 0, 0);
    }
    int c = nt * 16 + l15;
    float bir = b_ih[c],      bhr = b_hh[c];
    float biz = b_ih[c+128],  bhz = b_hh[c+128];
    float bin_= b_ih[c+256],  bhn = b_hh[c+256];
    #pragma unroll
    for (int reg = 0; reg < 4; ++reg) {
      int lr = quad * 4 + reg;
      float rgate = sigf(accr[reg] + bir + bhr);
      float zg = sigf(accz[reg] + biz + bhz);
      float ng = tanhf_fast(acci[reg] + bin_ + rgate * (acch[reg] + bhn));
      int ho = (lr * 256 + c * 2) ^ ((lr & 7) << 4);
      float hold = bf2f(*(const short*)((const char*)hin + ho));
      float hn2 = (1.f - zg) * ng + zg * hold;
      hbs[lr * 128 + c] = f2bf(hn2);
      hqs[lr * 128 + c] = f2fp8(hn2);
    }
  }
  __syncthreads();

  // ---- phase 7: coalesced copy-out ----
  if (tid < 256) {                       // hb: 2048 shorts = 256 lanes x 8
    int off16 = tid * 8;
    int grow = off16 >> 7;
    if (row0 + grow < M)
      *(uint4*)(hb_new + (size_t)row0 * 128 + off16) = *(const uint4*)&hbs[off16];
  } else if (tid < 384) {                // hq: 2048 bytes = 128 lanes x 16
    int offb = (tid - 256) * 16;
    int grow = offb >> 7;
    if (row0 + grow < M)
      *(uint4*)(hq_new + (size_t)row0 * 128 + offb) = *(const uint4*)&hqs[offb];
  }
}

// ---------- fc GEMM (256 cols) fused normalize+sigmoid + el/er; zq out is fp8 ----------
__global__ __launch_bounds__(256) void k_fc_eler(const short* __restrict__ Ab,
    const short* __restrict__ Bp, const float* __restrict__ attn_l,
    const float* __restrict__ attn_r, unsigned char* __restrict__ zq,
    float* __restrict__ el, float* __restrict__ er, int M) {
  int tid = threadIdx.x;
  int lane = tid & 63, wave = tid >> 6;
  int row0 = blockIdx.x * 128 + wave * 32;
  int quad = lane >> 4, l15 = lane & 15;
  short8 af[2][4];
  #pragma unroll
  for (int rt = 0; rt < 2; ++rt) {
    int ar = row0 + rt * 16 + l15; if (ar >= M) ar = M - 1;
    #pragma unroll
    for (int kt = 0; kt < 4; ++kt)
      af[rt][kt] = *(const short8*)(Ab + (size_t)ar * 128 + kt * 32 + quad * 8);
  }
  #pragma unroll
  for (int rt = 0; rt < 2; ++rt) {
    float ss = 0.f;
    #pragma unroll
    for (int kt = 0; kt < 4; ++kt)
      #pragma unroll
      for (int j = 0; j < 8; ++j) {
        float x = bf2f(af[rt][kt][j]);
        ss += x * x;
      }
    ss += __shfl_xor(ss, 16);
    ss += __shfl_xor(ss, 32);
    float inv = 1.f / fmaxf(sqrtf(ss), 1e-12f);
    #pragma unroll
    for (int kt = 0; kt < 4; ++kt)
      #pragma unroll
      for (int j = 0; j < 8; ++j)
        af[rt][kt][j] = f2bf(sigf(bf2f(af[rt][kt][j]) * inv));
  }
  float elp[2][2][4] = {};
  float erp[2][2][4] = {};
  for (int nt = 0; nt < 16; ++nt) {
    f32x4 a0 = {0.f,0.f,0.f,0.f}, a1 = {0.f,0.f,0.f,0.f};
    #pragma unroll
    for (int kt = 0; kt < 4; ++kt) {
      short8 b = *(const short8*)(Bp + (((size_t)(nt * 4 + kt) * 64) + lane) * 8);
      a0 = __builtin_amdgcn_mfma_f32_16x16x32_bf16(af[0][kt], b, a0, 0, 0, 0);
      a1 = __builtin_amdgcn_mfma_f32_16x16x32_bf16(af[1][kt], b, a1, 0, 0, 0);
    }
    int head = nt >> 3;
    int colh = (nt & 7) * 16 + l15;
    float alv = attn_l[head * 128 + colh];
    float arv = attn_r[head * 128 + colh];
    int c = nt * 16 + l15;
    #pragma unroll
    for (int rt = 0; rt < 2; ++rt) {
      f32x4 acc = rt ? a1 : a0;
      #pragma unroll
      for (int reg = 0; reg < 4; ++reg) {
        int r = row0 + rt * 16 + quad * 4 + reg;
        if (r < M) zq[(size_t)r * 256 + c] = f2fp8(acc[reg]);
        elp[rt][head][reg] += acc[reg] * alv;
        erp[rt][head][reg] += acc[reg] * arv;
      }
    }
  }
  #pragma unroll
  for (int off = 1; off < 16; off <<= 1) {
    #pragma unroll
    for (int rt = 0; rt < 2; ++rt)
      #pragma unroll
      for (int h = 0; h < 2; ++h)
        #pragma unroll
        for (int reg = 0; reg < 4; ++reg) {
          elp[rt][h][reg] += __shfl_xor(elp[rt][h][reg], off);
          erp[rt][h][reg] += __shfl_xor(erp[rt][h][reg], off);
        }
  }
  if (l15 == 0) {
    #pragma unroll
    for (int rt = 0; rt < 2; ++rt)
      #pragma unroll
      for (int h = 0; h < 2; ++h)
        #pragma unroll
        for (int reg = 0; reg < 4; ++reg) {
          int r = row0 + rt * 16 + quad * 4 + reg;
          if (r < M) {
            el[r * 2 + h] = elp[rt][h][reg];
            er[r * 2 + h] = erp[rt][h][reg];
          }
        }
  }
}

// ---------- GAT aggregation: no-max softmax + readlane-batched 8-deep fp8 gathers,
// packed f32x2 FMA accumulate (v_pk_fma_f32). Zeroes `sums` in first NG2 blocks. ----------
__global__ __launch_bounds__(256) void k_gat(const unsigned char* __restrict__ zq,
    const float* __restrict__ el, const float* __restrict__ er,
    const int* __restrict__ row_ofs, const int* __restrict__ csr_se,
    const float* __restrict__ gat_bias, short* __restrict__ outb,
    float* __restrict__ sums, int N) {
  if (blockIdx.x < NG2) sums[blockIdx.x * 256 + threadIdx.x] = 0.f;
  int node = blockIdx.x * 4 + (threadIdx.x >> 6);
  int lane = threadIdx.x & 63;
  if (node >= N) return;
  int beg = row_ofs[node], end = row_ofs[node + 1];
  float2 ern = ((const float2*)er)[node];
  float l0 = 0.f, l1 = 0.f;
  f32x2 a01 = {0.f, 0.f}, a23 = {0.f, 0.f};
  int head = lane >> 5;
  const char* elb = (const char*)el;
  const char* zqb = (const char*)zq;
  for (int base = beg; base < end; base += 64) {
    int nv = end - base; if (nv > 64) nv = 64;
    int se = (lane < nv) ? csr_se[base + lane] : 0;
    float p0 = 0.f, p1 = 0.f;
    if (lane < nv) {
      float2 els = *(const float2*)(elb + (se >> 7));   // se>>7 == src*8
      p0 = expf(lrelu(els.x + ern.x));
      p1 = expf(lrelu(els.y + ern.y));
    }
    float t0 = p0, t1 = p1;
    #pragma unroll
    for (int off = 32; off; off >>= 1) { t0 += __shfl_xor(t0, off); t1 += __shfl_xor(t1, off); }
    l0 += t0; l1 += t1;
    int w01 = (int)pk2(p0, p1);
    int j = 0;
    for (; j + 8 <= nv; j += 8) {
      int bb[8]; unsigned ww[8];
      #pragma unroll
      for (int k = 0; k < 8; ++k) {
        bb[k] = __builtin_amdgcn_readlane(se, j + k) >> 2;
        ww[k] = (unsigned)__builtin_amdgcn_readlane(w01, j + k);
      }
      unsigned zz[8];
      #pragma unroll
      for (int k = 0; k < 8; ++k)
        zz[k] = ((const unsigned*)(zqb + bb[k]))[lane];
      #pragma unroll
      for (int k = 0; k < 8; ++k) {
        float f = head ? bfhi(ww[k]) : bflo(ww[k]);
        f32x2 fv = {f, f};
        f32x2 lo = __builtin_amdgcn_cvt_pk_f32_fp8(zz[k], false);
        f32x2 hi = __builtin_amdgcn_cvt_pk_f32_fp8(zz[k], true);
        a01 = lo * fv + a01;
        a23 = hi * fv + a23;
      }
    }
    for (; j + 4 <= nv; j += 4) {
      int bb[4]; unsigned ww[4];
      #pragma unroll
      for (int k = 0; k < 4; ++k) {
        bb[k] = __builtin_amdgcn_readlane(se, j + k) >> 2;
        ww[k] = (unsigned)__builtin_amdgcn_readlane(w01, j + k);
      }
      unsigned zz[4];
      #pragma unroll
      for (int k = 0; k < 4; ++k)
        zz[k] = ((const unsigned*)(zqb + bb[k]))[lane];
      #pragma unroll
      for (int k = 0; k < 4; ++k) {
        float f = head ? bfhi(ww[k]) : bflo(ww[k]);
        f32x2 fv = {f, f};
        f32x2 lo = __builtin_amdgcn_cvt_pk_f32_fp8(zz[k], false);
        f32x2 hi = __builtin_amdgcn_cvt_pk_f32_fp8(zz[k], true);
        a01 = lo * fv + a01;
        a23 = hi * fv + a23;
      }
    }
    for (; j < nv; ++j) {
      int bj = __builtin_amdgcn_readlane(se, j) >> 2;
      unsigned wj = (unsigned)__builtin_amdgcn_readlane(w01, j);
      float w = head ? bfhi(wj) : bflo(wj);
      f32x2 fv = {w, w};
      unsigned zv = ((const unsigned*)(zqb + bj))[lane];
      f32x2 lo = __builtin_amdgcn_cvt_pk_f32_fp8(zv, false);
      f32x2 hi = __builtin_amdgcn_cvt_pk_f32_fp8(zv, true);
      a01 = lo * fv + a01;
      a23 = hi * fv + a23;
    }
  }
  float inv0 = (l0 > 0.f) ? 1.f / l0 : 0.f;
  float inv1 = (l1 > 0.f) ? 1.f / l1 : 0.f;
  float inv = head ? inv1 : inv0;
  float4 b = ((const float4*)gat_bias)[lane];
  float ox = fmaxf(a01[0] * inv + b.x, 0.f);
  float oy = fmaxf(a01[1] * inv + b.y, 0.f);
  float oz = fmaxf(a23[0] * inv + b.z, 0.f);
  float ow = fmaxf(a23[1] * inv + b.w, 0.f);
  ((uint2*)(outb + (size_t)node * 256))[lane] = make_uint2(pk2(ox, oy), pk2(oz, ow));
}

// ---------- parallel segmented per-graph sums (bf16 input) ----------
__global__ __launch_bounds__(256) void k_segred(const short* __restrict__ hgatb,
    const int* __restrict__ gidc, float* __restrict__ sums, int NT2) {
  int node0 = blockIdx.x * 128;
  int col = threadIdx.x;
  int end = node0 + 128; if (end > NT2) end = NT2;
  if (node0 >= NT2) return;
  float acc = 0.f;
  int gcur = gidc[node0];
  for (int n = node0; n < end; ++n) {
    int g = gidc[n];
    if (g != gcur) {
      atomicAdd(&sums[gcur * 256 + col], acc);
      acc = 0.f; gcur = g;
    }
    acc += bf2f(hgatb[(size_t)n * 256 + col]);
  }
  atomicAdd(&sums[gcur * 256 + col], acc);
}

// ---------- mean + classifier (parallel: one block per graph) ----------
__global__ __launch_bounds__(64) void k_classify(const float* __restrict__ sums,
    const int* __restrict__ gcnt, const float* __restrict__ W_cls,
    const float* __restrict__ b_cls, float* __restrict__ logits) {
  int g = blockIdx.x, tid = threadIdx.x;
  int hh = tid >> 5, c = tid & 31;
  float invc = 1.f / fmaxf((float)gcnt[g], 1.f);
  float acc = 0.f;
  for (int d = 0; d < D; ++d)
    acc += (sums[g * 256 + hh * D + d] * invc) * W_cls[c * D + d];
  logits[g * 64 + hh * 32 + c] = acc + b_cls[c];
}

// ---------- pairwise distance + softmax over heads (graph g vs g+64) ----------
__global__ __launch_bounds__(64) void k_final(const float* __restrict__ logits,
    float* __restrict__ out) {
  int g = threadIdx.x;
  if (g >= NG) return;
  float d[2];
  #pragma unroll
  for (int hh = 0; hh < 2; ++hh) {
    float s = 0.f;
    for (int c = 0; c < 32; ++c) {
      float df = logits[g * 64 + hh * 32 + c] - logits[(g + NG) * 64 + hh * 32 + c] + 1e-6f;
      s += df * df;
    }
    d[hh] = sqrtf(s);
  }
  float mx = fmaxf(d[0], d[1]);
  float e0 = expf(d[0] - mx), e1 = expf(d[1] - mx);
  float den = e0 + e1;
  out[g * 2] = e0 / den;
  out[g * 2 + 1] = e1 / den;
}

extern "C" void kernel_launch(void* const* d_in, const int* in_sizes, int n_in,
                              void* d_out, int out_size, void* d_ws, size_t ws_size,
                              hipStream_t stream) {
  const float* in_feat1 = (const float*)d_in[0];
  const float* in_feat2 = (const float*)d_in[1];
  const int* src1 = (const int*)d_in[2];
  const int* dst1 = (const int*)d_in[3];
  const int* ety1 = (const int*)d_in[4];
  const int* gid1 = (const int*)d_in[5];
  const int* src2 = (const int*)d_in[6];
  const int* dst2 = (const int*)d_in[7];
  const int* ety2 = (const int*)d_in[8];
  const int* gid2 = (const int*)d_in[9];
  const float* W_et = (const float*)d_in[10];
  const float* b_et = (const float*)d_in[11];
  const float* W_ih = (const float*)d_in[12];
  const float* W_hh = (const float*)d_in[13];
  const float* b_ih = (const float*)d_in[14];
  const float* b_hh = (const float*)d_in[15];
  const float* W_fc = (const float*)d_in[16];
  const float* attn_l = (const float*)d_in[17];
  const float* attn_r = (const float*)d_in[18];
  const float* gat_bias = (const float*)d_in[19];
  const float* W_cls = (const float*)d_in[20];
  const float* b_cls = (const float*)d_in[21];
  float* out = (float*)d_out;

  int N = in_sizes[0] / D;
  int E = in_sizes[2];
  int N2 = 2 * N, E2 = 2 * E;

  char* p = (char*)d_ws;
  auto alloc = [&](size_t bytes) -> void* {
    char* r = p;
    p += (bytes + 255) & ~(size_t)255;
    return (void*)r;
  };
  short* WaP  = (short*)alloc((size_t)512 * 128 * 2);
  short* WihP = (short*)alloc((size_t)384 * 128 * 2);
  short* WhhP = (short*)alloc((size_t)384 * 128 * 2);
  short* WfcP = (short*)alloc((size_t)256 * 128 * 2);
  short* hb0 = (short*)alloc((size_t)N2 * D * 2);
  short* hb1 = (short*)alloc((size_t)N2 * D * 2);
  unsigned char* hq0 = (unsigned char*)alloc((size_t)N2 * D);
  unsigned char* hq1 = (unsigned char*)alloc((size_t)N2 * D);
  short* hgatb = (short*)alloc((size_t)N2 * 256 * 2);  // GAT output (bf16)
  unsigned char* zq = (unsigned char*)alloc((size_t)N2 * 256); // fp8 zft
  float* el  = (float*)alloc((size_t)N2 * 2 * 4);
  float* er  = (float*)alloc((size_t)N2 * 2 * 4);
  float* sums= (float*)alloc((size_t)NG2 * 256 * 4);
  float* logits = (float*)alloc((size_t)NG2 * 64 * 4);
  int* deg     = (int*)alloc((size_t)N2 * 4);
  int* row_ofs = (int*)alloc(((size_t)N2 + 1) * 4);
  int* cursor  = (int*)alloc((size_t)N2 * 4);
  int* gidc    = (int*)alloc((size_t)N2 * 4);
  int* gcnt    = (int*)alloc((size_t)NG2 * 4);
  int* bsum    = (int*)alloc((size_t)1024 * 4);
  int* boffs   = (int*)alloc((size_t)1024 * 4);
  int* csr_se  = (int*)alloc((size_t)E2 * 4);
  if ((size_t)(p - (char*)d_ws) > ws_size) return;

  // setup: packs + init hb0/hq0 + zero deg/gcnt (single launch)
  k_setup<<<dim3(2048), dim3(256), 0, stream>>>(W_et, W_ih, W_hh, W_fc,
      in_feat1, in_feat2, WaP, WihP, WhhP, WfcP, hb0, hq0, deg, gcnt, N2, N * D / 4);

  // CSR for merged graph (XCD-sliced hist + scatter)
  int EB = 4800;              // edge blocks, multiple of 8 for slicing
  int GB = (N2 + 255) / 256;
  int nb = (N2 + 1023) / 1024;
  k_histgid<<<dim3(EB + GB), dim3(256), 0, stream>>>(dst1, dst2, gid1, gid2,
                                                     E, N, deg, gidc, gcnt, EB, N2);
  k_scan_a<<<dim3(nb), dim3(256), 0, stream>>>(deg, N2, bsum);
  k_scan_b<<<dim3(1), dim3(1024), 0, stream>>>(bsum, boffs, nb);
  k_scan_c<<<dim3(nb), dim3(256), 0, stream>>>(deg, boffs, row_ofs, cursor, N2);
  k_scatter<<<dim3(4800), dim3(256), 0, stream>>>(src1, dst1, ety1, src2, dst2, ety2,
                                                  E, N, cursor, csr_se, N2);

  int gb16 = (N2 + 15) / 16;
  int gb128 = (N2 + 127) / 128;
  int nb4 = (N2 + 3) / 4;

  short* hbp[2] = {hb0, hb1};
  unsigned char* hqp[2] = {hq0, hq1};
  for (int s = 0; s < NSTEPS; ++s) {
    k_step<<<dim3(gb16), dim3(1024), 0, stream>>>(
        hqp[s & 1], hbp[s & 1], hqp[(s + 1) & 1], hbp[(s + 1) & 1],
        row_ofs, csr_se, WaP, b_et, WihP, WhhP, b_ih, b_hh, N2);
  }
  short* hbf = hbp[NSTEPS & 1];
  k_fc_eler<<<dim3(gb128), dim3(256), 0, stream>>>(hbf, WfcP, attn_l, attn_r, zq, el, er, N2);
  k_gat<<<dim3(nb4), dim3(256), 0, stream>>>(zq, el, er, row_ofs, csr_se,
                                             gat_bias, hgatb, sums, N2);
  k_segred<<<dim3((N2 + 127) / 128), dim3(256), 0, stream>>>(hgatb, gidc, sums, N2);
  k_classify<<<dim3(NG2), dim3(64), 0, stream>>>(sums, gcnt, W_cls, b_cls, logits);
  k_final<<<dim3(1), dim3(64), 0, stream>>>(logits, out);
}

// Round 15
// 992.813 us; speedup vs baseline: 1.0133x; 1.0133x over previous
//
#include <hip/hip_runtime.h>
#include <math.h>

#define D 128
#define NG 64
#define NG2 128
#define NSTEPS 5

using short8 = __attribute__((ext_vector_type(8))) short;
using f32x4  = __attribute__((ext_vector_type(4))) float;
using f32x2  = __attribute__((ext_vector_type(2))) float;

// fast, overflow-safe transcendentals (v_exp_f32 + v_rcp_f32)
__device__ __forceinline__ float sigf(float x) {
  float e = __expf(-fabsf(x));
  float inv = __fdividef(1.f, 1.f + e);
  return x >= 0.f ? inv : e * inv;
}
__device__ __forceinline__ float tanhf_fast(float x) {
  float e = __expf(-2.f * fabsf(x));
  float r = (1.f - e) * __fdividef(1.f, 1.f + e);
  return x >= 0.f ? r : -r;
}
__device__ __forceinline__ float lrelu(float x) { return x > 0.f ? x : 0.2f * x; }
__device__ __forceinline__ short f2bf(float x) {
  unsigned u = __float_as_uint(x);
  u += 0x7fff + ((u >> 16) & 1);
  return (short)(u >> 16);
}
__device__ __forceinline__ unsigned pk2(float x, float y) {
  return ((unsigned)(unsigned short)f2bf(y) << 16) | (unsigned short)f2bf(x);
}
__device__ __forceinline__ float bflo(unsigned v) { return __uint_as_float(v << 16); }
__device__ __forceinline__ float bfhi(unsigned v) { return __uint_as_float(v & 0xffff0000u); }
__device__ __forceinline__ float bf2f(short s) {
  return __uint_as_float(((unsigned)(unsigned short)s) << 16);
}
__device__ __forceinline__ unsigned char f2fp8(float x) {
  int p = __builtin_amdgcn_cvt_pk_fp8_f32(x, x, 0, false);
  return (unsigned char)(p & 0xff);
}

// ---------- pack helpers ----------
__device__ __forceinline__ void packK128(const float* __restrict__ W,
                                         short* __restrict__ P, int i) {
  int j = i & 7;
  int lane = (i >> 3) & 63;
  int kt = (i >> 9) & 3;
  int nt = i >> 11;
  int c = nt * 16 + (lane & 15);
  int k = kt * 32 + ((lane >> 4) << 3) + j;
  P[i] = f2bf(W[c * 128 + k]);
}
__device__ __forceinline__ void packA512f(const float* __restrict__ W_et,
                                          short* __restrict__ P, int i) {
  int j = i & 7;
  int lane = (i >> 3) & 63;
  int kt = (i >> 9) & 15;
  int nt = i >> 13;
  int c = nt * 16 + (lane & 15);
  int k = kt * 32 + ((lane >> 4) << 3) + j;
  P[i] = f2bf(W_et[(k >> 7) * 16384 + c * 128 + (k & 127)]);
}

// ---------- mega setup: packs + init hb (bf16) + hq (fp8 shadow) + zero deg/gcnt ----------
__global__ __launch_bounds__(256) void k_setup(const float* __restrict__ W_et,
    const float* __restrict__ W_ih, const float* __restrict__ W_hh,
    const float* __restrict__ W_fc, const float* __restrict__ f1,
    const float* __restrict__ f2, short* __restrict__ WaP, short* __restrict__ WihP,
    short* __restrict__ WhhP, short* __restrict__ WfcP, short* __restrict__ hb,
    unsigned char* __restrict__ hq,
    int* __restrict__ deg, int* __restrict__ gcnt, int N2, int Nd4) {
  const int sA = 65536, sB = 49152, sC = 49152, sD = 32768;
  int sE = N2, sF = NG2;
  long sG = 2L * Nd4;
  long tot = (long)(sA + sB + sC + sD) + sE + sF + sG;
  for (long ii = (long)blockIdx.x * blockDim.x + threadIdx.x; ii < tot;
       ii += (long)gridDim.x * blockDim.x) {
    long r = ii;
    if (r < sA) { packA512f(W_et, WaP, (int)r); continue; }
    r -= sA;
    if (r < sB) { packK128(W_ih, WihP, (int)r); continue; }
    r -= sB;
    if (r < sC) { packK128(W_hh, WhhP, (int)r); continue; }
    r -= sC;
    if (r < sD) { packK128(W_fc, WfcP, (int)r); continue; }
    r -= sD;
    if (r < sE) { deg[r] = 0; continue; }
    r -= sE;
    if (r < sF) { gcnt[r] = 0; continue; }
    r -= sF;
    {
      int i = (int)r;
      float4 v = (i < Nd4) ? ((const float4*)f1)[i] : ((const float4*)f2)[i - Nd4];
      ((uint2*)hb)[i] = make_uint2(pk2(v.x, v.y), pk2(v.z, v.w));
      int q = __builtin_amdgcn_cvt_pk_fp8_f32(v.x, v.y, 0, false);
      q = __builtin_amdgcn_cvt_pk_fp8_f32(v.z, v.w, q, true);
      ((unsigned*)hq)[i] = (unsigned)q;
    }
  }
}

// ---------- hist (XCD-sliced edge blocks) + gid fill/count (node blocks) ----------
__global__ __launch_bounds__(256) void k_histgid(const int* __restrict__ dst1,
    const int* __restrict__ dst2, const int* __restrict__ gid1,
    const int* __restrict__ gid2, int E, int N, int* __restrict__ deg,
    int* __restrict__ gidc, int* __restrict__ gcnt, int EB, int N2) {
  __shared__ int cnt[NG2];
  if ((int)blockIdx.x < EB) {
    int slice = blockIdx.x & 7;
    int bls = blockIdx.x >> 3;
    int nbs = EB >> 3;
    int W = (N2 + 7) >> 3;
    int lo = slice * W, hi = lo + W;
    for (int e = bls * 256 + threadIdx.x; e < 2 * E; e += nbs * 256) {
      int d = (e < E) ? dst1[e] : dst2[e - E] + N;
      if (d >= lo && d < hi) atomicAdd(&deg[d], 1);
    }
  } else {
    int t = threadIdx.x;
    if (t < NG2) cnt[t] = 0;
    __syncthreads();
    int i = (blockIdx.x - EB) * 256 + t;
    if (i < 2 * N) {
      int g = (i < N) ? gid1[i] : gid2[i - N] + NG;
      gidc[i] = g;
      atomicAdd(&cnt[g], 1);
    }
    __syncthreads();
    if (t < NG2 && cnt[t]) atomicAdd(&gcnt[t], cnt[t]);
  }
}

__global__ __launch_bounds__(256) void k_scan_a(const int* __restrict__ deg, int n,
                                                int* __restrict__ bsum) {
  int base = blockIdx.x * 1024 + threadIdx.x * 4;
  int s = 0;
  if (base + 3 < n) {
    int4 v = *(const int4*)(deg + base);
    s = v.x + v.y + v.z + v.w;
  } else {
    for (int k = 0; k < 4; ++k) if (base + k < n) s += deg[base + k];
  }
  #pragma unroll
  for (int off = 32; off; off >>= 1) s += __shfl_xor(s, off);
  __shared__ int ws[4];
  if ((threadIdx.x & 63) == 0) ws[threadIdx.x >> 6] = s;
  __syncthreads();
  if (threadIdx.x == 0) bsum[blockIdx.x] = ws[0] + ws[1] + ws[2] + ws[3];
}

__global__ __launch_bounds__(1024) void k_scan_b(const int* __restrict__ bsum,
                                                 int* __restrict__ boffs, int nb) {
  int tid = threadIdx.x;
  int v = (tid < nb) ? bsum[tid] : 0;
  int lane = tid & 63, wv = tid >> 6;
  int x = v;
  #pragma unroll
  for (int off = 1; off < 64; off <<= 1) {
    int y = __shfl_up(x, off);
    if (lane >= off) x += y;
  }
  __shared__ int wsum[16];
  if (lane == 63) wsum[wv] = x;
  __syncthreads();
  if (tid < 16) {
    int u = wsum[tid];
    #pragma unroll
    for (int off = 1; off < 16; off <<= 1) {
      int y = __shfl_up(u, off);
      if (tid >= off) u += y;
    }
    wsum[tid] = u;
  }
  __syncthreads();
  int woff = wv ? wsum[wv - 1] : 0;
  if (tid < nb) boffs[tid] = woff + x - v;
}

__global__ __launch_bounds__(256) void k_scan_c(const int* __restrict__ deg,
    const int* __restrict__ boffs, int* __restrict__ row_ofs,
    int* __restrict__ cursor, int n) {
  int base = blockIdx.x * 1024 + threadIdx.x * 4;
  int v[4] = {0, 0, 0, 0};
  if (base + 3 < n) {
    int4 t = *(const int4*)(deg + base);
    v[0] = t.x; v[1] = t.y; v[2] = t.z; v[3] = t.w;
  } else {
    for (int k = 0; k < 4; ++k) if (base + k < n) v[k] = deg[base + k];
  }
  int s = v[0] + v[1] + v[2] + v[3];
  int lane = threadIdx.x & 63, wv = threadIdx.x >> 6;
  int x = s;
  #pragma unroll
  for (int off = 1; off < 64; off <<= 1) {
    int y = __shfl_up(x, off);
    if (lane >= off) x += y;
  }
  __shared__ int wsum[4];
  if (lane == 63) wsum[wv] = x;
  __syncthreads();
  int woff = 0;
  for (int w = 0; w < wv; ++w) woff += wsum[w];
  int run = boffs[blockIdx.x] + woff + x - s;
  #pragma unroll
  for (int k = 0; k < 4; ++k) {
    int i = base + k;
    if (i < n) {
      cursor[i] = run;
      run += v[k];
      row_ofs[i + 1] = run;
    }
  }
  if (blockIdx.x == 0 && threadIdx.x == 0) row_ofs[0] = 0;
}

// scatter: csr_se = src*1024 + etype. XCD-sliced by dst (blockIdx&7 = slice).
__global__ __launch_bounds__(256) void k_scatter(const int* __restrict__ src1,
    const int* __restrict__ dst1, const int* __restrict__ ety1,
    const int* __restrict__ src2, const int* __restrict__ dst2,
    const int* __restrict__ ety2, int E, int N, int* __restrict__ cursor,
    int* __restrict__ csr_se, int N2) {
  int slice = blockIdx.x & 7;
  int bls = blockIdx.x >> 3;
  int nbs = gridDim.x >> 3;
  int W = (N2 + 7) >> 3;
  int lo = slice * W, hi = lo + W;
  for (int e = bls * 256 + threadIdx.x; e < 2 * E; e += nbs * 256) {
    int d = (e < E) ? dst1[e] : dst2[e - E] + N;
    if (d < lo || d >= hi) continue;
    int s, et;
    if (e < E) { s = src1[e]; et = ety1[e]; }
    else { s = src2[e - E] + N; et = ety2[e - E]; }
    int p = atomicAdd(&cursor[d], 1);
    csr_se[p] = (s << 10) + et;
  }
}

// ---------- FULLY FUSED STEP (r10 structure, verified 136 us): fp8 gather
// (1 node/wave) -> et-GEMM (LDS) -> GRU -> hb/hq new. Double-buffered h. ----------
__global__ __launch_bounds__(1024) void k_step(const unsigned char* __restrict__ hq_old,
    const short* __restrict__ hb_old, unsigned char* __restrict__ hq_new,
    short* __restrict__ hb_new,
    const int* __restrict__ row_ofs, const int* __restrict__ csr_se,
    const short* __restrict__ WaP, const float* __restrict__ b_et,
    const short* __restrict__ Pih, const short* __restrict__ Phh,
    const float* __restrict__ b_ih, const float* __restrict__ b_hh, int M) {
  __shared__ short Stile[16 * 512];        // 16 KB per-etype sums, swizzled
  __shared__ float lcnt[16][4];
  __shared__ short abt[16 * 128];          // 4 KB ab tile, swizzled
  __shared__ short hin[16 * 128];          // 4 KB hb_old tile, swizzled
  __shared__ short hbs[16 * 128];          // 4 KB out bf16
  __shared__ unsigned char hqs[16 * 128];  // 2 KB out fp8
  int tid = threadIdx.x;
  int lane = tid & 63, wave = tid >> 6;   // wave = 0..15
  int row0 = blockIdx.x * 16;
  int quad = lane >> 4, l15 = lane & 15;

  // ---- phase 1: per-etype fp8 gather; wave handles node row0 + wave ----
  {
    int li = wave;
    int node = row0 + li;
    f32x2 A0 = {0.f, 0.f}, A1 = {0.f, 0.f}, A2 = {0.f, 0.f}, A3 = {0.f, 0.f};
    int c0 = 0, c1 = 0, c2 = 0, c3 = 0;
    const char* hqb = (const char*)hq_old;
    if (node < M) {
      int beg = row_ofs[node], end = row_ofs[node + 1];
      #define ACC(ET, V) do { \
          f32x2 t_ = __builtin_amdgcn_cvt_pk_f32_fp8((unsigned)(V), false); \
          if (ET == 0)      { A0 += t_; ++c0; } \
          else if (ET == 1) { A1 += t_; ++c1; } \
          else if (ET == 2) { A2 += t_; ++c2; } \
          else              { A3 += t_; ++c3; } } while (0)
      for (int base = beg; base < end; base += 64) {
        int nv = end - base; if (nv > 64) nv = 64;
        int r = (lane < nv) ? csr_se[base + lane] : 0;
        int j = 0;
        for (; j + 16 <= nv; j += 16) {
          int rr[16];
          #pragma unroll
          for (int k = 0; k < 16; ++k) rr[k] = __builtin_amdgcn_readlane(r, j + k);
          unsigned short v[16];
          #pragma unroll
          for (int k = 0; k < 16; ++k)
            v[k] = ((const unsigned short*)(hqb + (rr[k] >> 3)))[lane];
          #pragma unroll
          for (int k = 0; k < 16; ++k) ACC(rr[k] & 3, v[k]);
        }
        for (; j + 8 <= nv; j += 8) {
          int rr[8];
          #pragma unroll
          for (int k = 0; k < 8; ++k) rr[k] = __builtin_amdgcn_readlane(r, j + k);
          unsigned short v[8];
          #pragma unroll
          for (int k = 0; k < 8; ++k)
            v[k] = ((const unsigned short*)(hqb + (rr[k] >> 3)))[lane];
          #pragma unroll
          for (int k = 0; k < 8; ++k) ACC(rr[k] & 3, v[k]);
        }
        for (; j + 4 <= nv; j += 4) {
          int rr[4];
          #pragma unroll
          for (int k = 0; k < 4; ++k) rr[k] = __builtin_amdgcn_readlane(r, j + k);
          unsigned short v[4];
          #pragma unroll
          for (int k = 0; k < 4; ++k)
            v[k] = ((const unsigned short*)(hqb + (rr[k] >> 3)))[lane];
          #pragma unroll
          for (int k = 0; k < 4; ++k) ACC(rr[k] & 3, v[k]);
        }
        for (; j < nv; ++j) {
          int rr = __builtin_amdgcn_readlane(r, j);
          unsigned short v = ((const unsigned short*)(hqb + (rr >> 3)))[lane];
          ACC(rr & 3, v);
        }
      }
      #undef ACC
    }
    int swz = (li & 7) << 4;
    unsigned* ld = (unsigned*)Stile;
    ld[(li * 1024 + ((lane * 4      ) ^ swz)) >> 2] = pk2(A0[0], A0[1]);
    ld[(li * 1024 + ((lane * 4 + 256) ^ swz)) >> 2] = pk2(A1[0], A1[1]);
    ld[(li * 1024 + ((lane * 4 + 512) ^ swz)) >> 2] = pk2(A2[0], A2[1]);
    ld[(li * 1024 + ((lane * 4 + 768) ^ swz)) >> 2] = pk2(A3[0], A3[1]);
    if (lane == 0) {
      lcnt[li][0] = (float)c0; lcnt[li][1] = (float)c1;
      lcnt[li][2] = (float)c2; lcnt[li][3] = (float)c3;
    }
  }
  __syncthreads();

  // ---- phase 3: waves 0-7 et-GEMM -> abt; waves 8-11 stage hb_old -> hin ----
  if (wave < 8) {
    int swz = (l15 & 7) << 4;
    int nt = wave;
    f32x4 acc = {0.f, 0.f, 0.f, 0.f};
    #pragma unroll
    for (int kt = 0; kt < 16; ++kt) {
      int boff = l15 * 1024 + ((kt * 64 + quad * 16) ^ swz);
      short8 a = *(const short8*)((const char*)Stile + boff);
      short8 b = *(const short8*)(WaP + (((size_t)(nt * 16 + kt) * 64) + lane) * 8);
      acc = __builtin_amdgcn_mfma_f32_16x16x32_bf16(a, b, acc, 0, 0, 0);
    }
    int c = nt * 16 + l15;
    float be0 = b_et[c], be1 = b_et[128 + c], be2 = b_et[256 + c], be3 = b_et[384 + c];
    #pragma unroll
    for (int reg = 0; reg < 4; ++reg) {
      int lr = quad * 4 + reg;
      float v = acc[reg] + lcnt[lr][0] * be0 + lcnt[lr][1] * be1
                         + lcnt[lr][2] * be2 + lcnt[lr][3] * be3;
      int bo = (lr * 256 + c * 2) ^ ((lr & 7) << 4);
      *(short*)((char*)abt + bo) = f2bf(v);
    }
  } else if (wave < 12) {
    int t2 = tid - 512;                  // 0..255
    int row = t2 >> 4;                   // 16 rows
    int col8 = t2 & 15;                  // 16 chunks of 8 shorts
    int r = row0 + row;
    uint4 v = make_uint4(0, 0, 0, 0);
    if (r < M) v = *(const uint4*)(hb_old + (size_t)r * 128 + col8 * 8);
    int bo = (row * 256 + col8 * 16) ^ ((row & 7) << 4);
    *(uint4*)((char*)hin + bo) = v;
  }
  __syncthreads();

  // ---- phase 5: waves 0-7 GRU; wave owns output col tile nt = wave ----
  if (wave < 8) {
    int nt = wave;
    size_t li = ((size_t)lane) * 8;
    f32x4 accr = {0.f,0.f,0.f,0.f}, accz = {0.f,0.f,0.f,0.f};
    f32x4 acci = {0.f,0.f,0.f,0.f}, acch = {0.f,0.f,0.f,0.f};
    #pragma unroll
    for (int kt = 0; kt < 4; ++kt) {
      int ao = (l15 * 256 + (kt * 64 + quad * 16)) ^ ((l15 & 7) << 4);
      short8 fa = *(const short8*)((const char*)abt + ao);
      short8 fh = *(const short8*)((const char*)hin + ao);
      short8 wr = *(const short8*)(Pih + ((size_t)((nt     ) * 4 + kt) * 64) * 8 + li);
      short8 wz = *(const short8*)(Pih + ((size_t)((nt +  8) * 4 + kt) * 64) * 8 + li);
      short8 wn = *(const short8*)(Pih + ((size_t)((nt + 16) * 4 + kt) * 64) * 8 + li);
      short8 ur = *(const short8*)(Phh + ((size_t)((nt     ) * 4 + kt) * 64) * 8 + li);
      short8 uz = *(const short8*)(Phh + ((size_t)((nt +  8) * 4 + kt) * 64) * 8 + li);
      short8 un = *(const short8*)(Phh + ((size_t)((nt + 16) * 4 + kt) * 64) * 8 + li);
      accr = __builtin_amdgcn_mfma_f32_16x16x32_bf16(fa, wr, accr, 0, 0, 0);
      accr = __builtin_amdgcn_mfma_f32_16x16x32_bf16(fh, ur, accr, 0, 0, 0);
      accz = __builtin_amdgcn_mfma_f32_16x16x32_bf16(fa, wz, accz, 0, 0, 0);
      accz = __builtin_amdgcn_mfma_f32_16x16x32_bf16(fh, uz, accz, 0, 0, 0);
      acci = __builtin_amdgcn_mfma_f32_16x16x32_bf16(fa, wn, acci, 0, 0, 0);
      acch = __builtin_amdgcn_mfma_f32_16x16x32_bf16(fh, un, acch, 0, 0, 0);
    }
    int c = nt * 16 + l15;
    float bir = b_ih[c],      bhr = b_hh[c];
    float biz = b_ih[c+128],  bhz = b_hh[c+128];
    float bin_= b_ih[c+256],  bhn = b_hh[c+256];
    #pragma unroll
    for (int reg = 0; reg < 4; ++reg) {
      int lr = quad * 4 + reg;
      float rgate = sigf(accr[reg] + bir + bhr);
      float zg = sigf(accz[reg] + biz + bhz);
      float ng = tanhf_fast(acci[reg] + bin_ + rgate * (acch[reg] + bhn));
      int ho = (lr * 256 + c * 2) ^ ((lr & 7) << 4);
      float hold = bf2f(*(const short*)((const char*)hin + ho));
      float hn2 = (1.f - zg) * ng + zg * hold;
      hbs[lr * 128 + c] = f2bf(hn2);
      hqs[lr * 128 + c] = f2fp8(hn2);
    }
  }
  __syncthreads();

  // ---- phase 7: coalesced copy-out ----
  if (tid < 256) {                       // hb: 2048 shorts = 256 lanes x 8
    int off16 = tid * 8;
    int grow = off16 >> 7;
    if (row0 + grow < M)
      *(uint4*)(hb_new + (size_t)row0 * 128 + off16) = *(const uint4*)&hbs[off16];
  } else if (tid < 384) {                // hq: 2048 bytes = 128 lanes x 16
    int offb = (tid - 256) * 16;
    int grow = offb >> 7;
    if (row0 + grow < M)
      *(uint4*)(hq_new + (size_t)row0 * 128 + offb) = *(const uint4*)&hqs[offb];
  }
}

// ---------- fc GEMM (256 cols) fused normalize+sigmoid + el/er; zq out is fp8 ----------
__global__ __launch_bounds__(256) void k_fc_eler(const short* __restrict__ Ab,
    const short* __restrict__ Bp, const float* __restrict__ attn_l,
    const float* __restrict__ attn_r, unsigned char* __restrict__ zq,
    float* __restrict__ el, float* __restrict__ er, int M) {
  int tid = threadIdx.x;
  int lane = tid & 63, wave = tid >> 6;
  int row0 = blockIdx.x * 128 + wave * 32;
  int quad = lane >> 4, l15 = lane & 15;
  short8 af[2][4];
  #pragma unroll
  for (int rt = 0; rt < 2; ++rt) {
    int ar = row0 + rt * 16 + l15; if (ar >= M) ar = M - 1;
    #pragma unroll
    for (int kt = 0; kt < 4; ++kt)
      af[rt][kt] = *(const short8*)(Ab + (size_t)ar * 128 + kt * 32 + quad * 8);
  }
  #pragma unroll
  for (int rt = 0; rt < 2; ++rt) {
    float ss = 0.f;
    #pragma unroll
    for (int kt = 0; kt < 4; ++kt)
      #pragma unroll
      for (int j = 0; j < 8; ++j) {
        float x = bf2f(af[rt][kt][j]);
        ss += x * x;
      }
    ss += __shfl_xor(ss, 16);
    ss += __shfl_xor(ss, 32);
    float inv = 1.f / fmaxf(sqrtf(ss), 1e-12f);
    #pragma unroll
    for (int kt = 0; kt < 4; ++kt)
      #pragma unroll
      for (int j = 0; j < 8; ++j)
        af[rt][kt][j] = f2bf(sigf(bf2f(af[rt][kt][j]) * inv));
  }
  float elp[2][2][4] = {};
  float erp[2][2][4] = {};
  for (int nt = 0; nt < 16; ++nt) {
    f32x4 a0 = {0.f,0.f,0.f,0.f}, a1 = {0.f,0.f,0.f,0.f};
    #pragma unroll
    for (int kt = 0; kt < 4; ++kt) {
      short8 b = *(const short8*)(Bp + (((size_t)(nt * 4 + kt) * 64) + lane) * 8);
      a0 = __builtin_amdgcn_mfma_f32_16x16x32_bf16(af[0][kt], b, a0, 0, 0, 0);
      a1 = __builtin_amdgcn_mfma_f32_16x16x32_bf16(af[1][kt], b, a1, 0, 0, 0);
    }
    int head = nt >> 3;
    int colh = (nt & 7) * 16 + l15;
    float alv = attn_l[head * 128 + colh];
    float arv = attn_r[head * 128 + colh];
    int c = nt * 16 + l15;
    #pragma unroll
    for (int rt = 0; rt < 2; ++rt) {
      f32x4 acc = rt ? a1 : a0;
      #pragma unroll
      for (int reg = 0; reg < 4; ++reg) {
        int r = row0 + rt * 16 + quad * 4 + reg;
        if (r < M) zq[(size_t)r * 256 + c] = f2fp8(acc[reg]);
        elp[rt][head][reg] += acc[reg] * alv;
        erp[rt][head][reg] += acc[reg] * arv;
      }
    }
  }
  #pragma unroll
  for (int off = 1; off < 16; off <<= 1) {
    #pragma unroll
    for (int rt = 0; rt < 2; ++rt)
      #pragma unroll
      for (int h = 0; h < 2; ++h)
        #pragma unroll
        for (int reg = 0; reg < 4; ++reg) {
          elp[rt][h][reg] += __shfl_xor(elp[rt][h][reg], off);
          erp[rt][h][reg] += __shfl_xor(erp[rt][h][reg], off);
        }
  }
  if (l15 == 0) {
    #pragma unroll
    for (int rt = 0; rt < 2; ++rt)
      #pragma unroll
      for (int h = 0; h < 2; ++h)
        #pragma unroll
        for (int reg = 0; reg < 4; ++reg) {
          int r = row0 + rt * 16 + quad * 4 + reg;
          if (r < M) {
            el[r * 2 + h] = elp[rt][h][reg];
            er[r * 2 + h] = erp[rt][h][reg];
          }
        }
  }
}

// ---------- GAT aggregation: no-max softmax + readlane-batched 8-deep fp8 gathers,
// packed f32x2 FMA accumulate (v_pk_fma_f32). Zeroes `sums` in first NG2 blocks. ----------
__global__ __launch_bounds__(256) void k_gat(const unsigned char* __restrict__ zq,
    const float* __restrict__ el, const float* __restrict__ er,
    const int* __restrict__ row_ofs, const int* __restrict__ csr_se,
    const float* __restrict__ gat_bias, short* __restrict__ outb,
    float* __restrict__ sums, int N) {
  if (blockIdx.x < NG2) sums[blockIdx.x * 256 + threadIdx.x] = 0.f;
  int node = blockIdx.x * 4 + (threadIdx.x >> 6);
  int lane = threadIdx.x & 63;
  if (node >= N) return;
  int beg = row_ofs[node], end = row_ofs[node + 1];
  float2 ern = ((const float2*)er)[node];
  float l0 = 0.f, l1 = 0.f;
  f32x2 a01 = {0.f, 0.f}, a23 = {0.f, 0.f};
  int head = lane >> 5;
  const char* elb = (const char*)el;
  const char* zqb = (const char*)zq;
  for (int base = beg; base < end; base += 64) {
    int nv = end - base; if (nv > 64) nv = 64;
    int se = (lane < nv) ? csr_se[base + lane] : 0;
    float p0 = 0.f, p1 = 0.f;
    if (lane < nv) {
      float2 els = *(const float2*)(elb + (se >> 7));   // se>>7 == src*8
      p0 = expf(lrelu(els.x + ern.x));
      p1 = expf(lrelu(els.y + ern.y));
    }
    float t0 = p0, t1 = p1;
    #pragma unroll
    for (int off = 32; off; off >>= 1) { t0 += __shfl_xor(t0, off); t1 += __shfl_xor(t1, off); }
    l0 += t0; l1 += t1;
    int w01 = (int)pk2(p0, p1);
    int j = 0;
    for (; j + 8 <= nv; j += 8) {
      int bb[8]; unsigned ww[8];
      #pragma unroll
      for (int k = 0; k < 8; ++k) {
        bb[k] = __builtin_amdgcn_readlane(se, j + k) >> 2;
        ww[k] = (unsigned)__builtin_amdgcn_readlane(w01, j + k);
      }
      unsigned zz[8];
      #pragma unroll
      for (int k = 0; k < 8; ++k)
        zz[k] = ((const unsigned*)(zqb + bb[k]))[lane];
      #pragma unroll
      for (int k = 0; k < 8; ++k) {
        float f = head ? bfhi(ww[k]) : bflo(ww[k]);
        f32x2 fv = {f, f};
        f32x2 lo = __builtin_amdgcn_cvt_pk_f32_fp8(zz[k], false);
        f32x2 hi = __builtin_amdgcn_cvt_pk_f32_fp8(zz[k], true);
        a01 = lo * fv + a01;
        a23 = hi * fv + a23;
      }
    }
    for (; j + 4 <= nv; j += 4) {
      int bb[4]; unsigned ww[4];
      #pragma unroll
      for (int k = 0; k < 4; ++k) {
        bb[k] = __builtin_amdgcn_readlane(se, j + k) >> 2;
        ww[k] = (unsigned)__builtin_amdgcn_readlane(w01, j + k);
      }
      unsigned zz[4];
      #pragma unroll
      for (int k = 0; k < 4; ++k)
        zz[k] = ((const unsigned*)(zqb + bb[k]))[lane];
      #pragma unroll
      for (int k = 0; k < 4; ++k) {
        float f = head ? bfhi(ww[k]) : bflo(ww[k]);
        f32x2 fv = {f, f};
        f32x2 lo = __builtin_amdgcn_cvt_pk_f32_fp8(zz[k], false);
        f32x2 hi = __builtin_amdgcn_cvt_pk_f32_fp8(zz[k], true);
        a01 = lo * fv + a01;
        a23 = hi * fv + a23;
      }
    }
    for (; j < nv; ++j) {
      int bj = __builtin_amdgcn_readlane(se, j) >> 2;
      unsigned wj = (unsigned)__builtin_amdgcn_readlane(w01, j);
      float w = head ? bfhi(wj) : bflo(wj);
      f32x2 fv = {w, w};
      unsigned zv = ((const unsigned*)(zqb + bj))[lane];
      f32x2 lo = __builtin_amdgcn_cvt_pk_f32_fp8(zv, false);
      f32x2 hi = __builtin_amdgcn_cvt_pk_f32_fp8(zv, true);
      a01 = lo * fv + a01;
      a23 = hi * fv + a23;
    }
  }
  float inv0 = (l0 > 0.f) ? 1.f / l0 : 0.f;
  float inv1 = (l1 > 0.f) ? 1.f / l1 : 0.f;
  float inv = head ? inv1 : inv0;
  float4 b = ((const float4*)gat_bias)[lane];
  float ox = fmaxf(a01[0] * inv + b.x, 0.f);
  float oy = fmaxf(a01[1] * inv + b.y, 0.f);
  float oz = fmaxf(a23[0] * inv + b.z, 0.f);
  float ow = fmaxf(a23[1] * inv + b.w, 0.f);
  ((uint2*)(outb + (size_t)node * 256))[lane] = make_uint2(pk2(ox, oy), pk2(oz, ow));
}

// ---------- parallel segmented per-graph sums (bf16 input) ----------
__global__ __launch_bounds__(256) void k_segred(const short* __restrict__ hgatb,
    const int* __restrict__ gidc, float* __restrict__ sums, int NT2) {
  int node0 = blockIdx.x * 128;
  int col = threadIdx.x;
  int end = node0 + 128; if (end > NT2) end = NT2;
  if (node0 >= NT2) return;
  float acc = 0.f;
  int gcur = gidc[node0];
  for (int n = node0; n < end; ++n) {
    int g = gidc[n];
    if (g != gcur) {
      atomicAdd(&sums[gcur * 256 + col], acc);
      acc = 0.f; gcur = g;
    }
    acc += bf2f(hgatb[(size_t)n * 256 + col]);
  }
  atomicAdd(&sums[gcur * 256 + col], acc);
}

// ---------- mean + classifier (parallel: one block per graph) ----------
__global__ __launch_bounds__(64) void k_classify(const float* __restrict__ sums,
    const int* __restrict__ gcnt, const float* __restrict__ W_cls,
    const float* __restrict__ b_cls, float* __restrict__ logits) {
  int g = blockIdx.x, tid = threadIdx.x;
  int hh = tid >> 5, c = tid & 31;
  float invc = 1.f / fmaxf((float)gcnt[g], 1.f);
  float acc = 0.f;
  for (int d = 0; d < D; ++d)
    acc += (sums[g * 256 + hh * D + d] * invc) * W_cls[c * D + d];
  logits[g * 64 + hh * 32 + c] = acc + b_cls[c];
}

// ---------- pairwise distance + softmax over heads (graph g vs g+64) ----------
__global__ __launch_bounds__(64) void k_final(const float* __restrict__ logits,
    float* __restrict__ out) {
  int g = threadIdx.x;
  if (g >= NG) return;
  float d[2];
  #pragma unroll
  for (int hh = 0; hh < 2; ++hh) {
    float s = 0.f;
    for (int c = 0; c < 32; ++c) {
      float df = logits[g * 64 + hh * 32 + c] - logits[(g + NG) * 64 + hh * 32 + c] + 1e-6f;
      s += df * df;
    }
    d[hh] = sqrtf(s);
  }
  float mx = fmaxf(d[0], d[1]);
  float e0 = expf(d[0] - mx), e1 = expf(d[1] - mx);
  float den = e0 + e1;
  out[g * 2] = e0 / den;
  out[g * 2 + 1] = e1 / den;
}

extern "C" void kernel_launch(void* const* d_in, const int* in_sizes, int n_in,
                              void* d_out, int out_size, void* d_ws, size_t ws_size,
                              hipStream_t stream) {
  const float* in_feat1 = (const float*)d_in[0];
  const float* in_feat2 = (const float*)d_in[1];
  const int* src1 = (const int*)d_in[2];
  const int* dst1 = (const int*)d_in[3];
  const int* ety1 = (const int*)d_in[4];
  const int* gid1 = (const int*)d_in[5];
  const int* src2 = (const int*)d_in[6];
  const int* dst2 = (const int*)d_in[7];
  const int* ety2 = (const int*)d_in[8];
  const int* gid2 = (const int*)d_in[9];
  const float* W_et = (const float*)d_in[10];
  const float* b_et = (const float*)d_in[11];
  const float* W_ih = (const float*)d_in[12];
  const float* W_hh = (const float*)d_in[13];
  const float* b_ih = (const float*)d_in[14];
  const float* b_hh = (const float*)d_in[15];
  const float* W_fc = (const float*)d_in[16];
  const float* attn_l = (const float*)d_in[17];
  const float* attn_r = (const float*)d_in[18];
  const float* gat_bias = (const float*)d_in[19];
  const float* W_cls = (const float*)d_in[20];
  const float* b_cls = (const float*)d_in[21];
  float* out = (float*)d_out;

  int N = in_sizes[0] / D;
  int E = in_sizes[2];
  int N2 = 2 * N, E2 = 2 * E;

  char* p = (char*)d_ws;
  auto alloc = [&](size_t bytes) -> void* {
    char* r = p;
    p += (bytes + 255) & ~(size_t)255;
    return (void*)r;
  };
  short* WaP  = (short*)alloc((size_t)512 * 128 * 2);
  short* WihP = (short*)alloc((size_t)384 * 128 * 2);
  short* WhhP = (short*)alloc((size_t)384 * 128 * 2);
  short* WfcP = (short*)alloc((size_t)256 * 128 * 2);
  short* hb0 = (short*)alloc((size_t)N2 * D * 2);
  short* hb1 = (short*)alloc((size_t)N2 * D * 2);
  unsigned char* hq0 = (unsigned char*)alloc((size_t)N2 * D);
  unsigned char* hq1 = (unsigned char*)alloc((size_t)N2 * D);
  short* hgatb = (short*)alloc((size_t)N2 * 256 * 2);  // GAT output (bf16)
  unsigned char* zq = (unsigned char*)alloc((size_t)N2 * 256); // fp8 zft
  float* el  = (float*)alloc((size_t)N2 * 2 * 4);
  float* er  = (float*)alloc((size_t)N2 * 2 * 4);
  float* sums= (float*)alloc((size_t)NG2 * 256 * 4);
  float* logits = (float*)alloc((size_t)NG2 * 64 * 4);
  int* deg     = (int*)alloc((size_t)N2 * 4);
  int* row_ofs = (int*)alloc(((size_t)N2 + 1) * 4);
  int* cursor  = (int*)alloc((size_t)N2 * 4);
  int* gidc    = (int*)alloc((size_t)N2 * 4);
  int* gcnt    = (int*)alloc((size_t)NG2 * 4);
  int* bsum    = (int*)alloc((size_t)1024 * 4);
  int* boffs   = (int*)alloc((size_t)1024 * 4);
  int* csr_se  = (int*)alloc((size_t)E2 * 4);
  if ((size_t)(p - (char*)d_ws) > ws_size) return;

  // setup: packs + init hb0/hq0 + zero deg/gcnt (single launch)
  k_setup<<<dim3(2048), dim3(256), 0, stream>>>(W_et, W_ih, W_hh, W_fc,
      in_feat1, in_feat2, WaP, WihP, WhhP, WfcP, hb0, hq0, deg, gcnt, N2, N * D / 4);

  // CSR for merged graph (XCD-sliced hist + scatter)
  int EB = 4800;              // edge blocks, multiple of 8 for slicing
  int GB = (N2 + 255) / 256;
  int nb = (N2 + 1023) / 1024;
  k_histgid<<<dim3(EB + GB), dim3(256), 0, stream>>>(dst1, dst2, gid1, gid2,
                                                     E, N, deg, gidc, gcnt, EB, N2);
  k_scan_a<<<dim3(nb), dim3(256), 0, stream>>>(deg, N2, bsum);
  k_scan_b<<<dim3(1), dim3(1024), 0, stream>>>(bsum, boffs, nb);
  k_scan_c<<<dim3(nb), dim3(256), 0, stream>>>(deg, boffs, row_ofs, cursor, N2);
  k_scatter<<<dim3(4800), dim3(256), 0, stream>>>(src1, dst1, ety1, src2, dst2, ety2,
                                                  E, N, cursor, csr_se, N2);

  int gb16 = (N2 + 15) / 16;
  int gb128 = (N2 + 127) / 128;
  int nb4 = (N2 + 3) / 4;

  short* hbp[2] = {hb0, hb1};
  unsigned char* hqp[2] = {hq0, hq1};
  for (int s = 0; s < NSTEPS; ++s) {
    k_step<<<dim3(gb16), dim3(1024), 0, stream>>>(
        hqp[s & 1], hbp[s & 1], hqp[(s + 1) & 1], hbp[(s + 1) & 1],
        row_ofs, csr_se, WaP, b_et, WihP, WhhP, b_ih, b_hh, N2);
  }
  short* hbf = hbp[NSTEPS & 1];
  k_fc_eler<<<dim3(gb128), dim3(256), 0, stream>>>(hbf, WfcP, attn_l, attn_r, zq, el, er, N2);
  k_gat<<<dim3(nb4), dim3(256), 0, stream>>>(zq, el, er, row_ofs, csr_se,
                                             gat_bias, hgatb, sums, N2);
  k_segred<<<dim3((N2 + 127) / 128), dim3(256), 0, stream>>>(hgatb, gidc, sums, N2);
  k_classify<<<dim3(NG2), dim3(64), 0, stream>>>(sums, gcnt, W_cls, b_cls, logits);
  k_final<<<dim3(1), dim3(64), 0, stream>>>(logits, out);
}